// Round 1
// baseline (123.347 us; speedup 1.0000x reference)
//
#include <hip/hip_runtime.h>
#include <math.h>

#define NB 16
#define NS 4096
#define ND 1024
#define NH 16
#define LUTN 4096
#define TS 64        // s-rows per block in k_scores
#define NCHUNK 64    // s-chunks in k_ctx

#define KF   651.8986469044033f      // LUT_SIZE / (2*pi)
#define PHIF 1.6180339887498949f
#define ANGF 0.0015339807878856412f  // 2*pi / LUT_SIZE
#define INV_SCALE (1.0f / 11.313708498984761f)  // 1/sqrt(2*dh)

// workspace layout, in floats
#define OFF_LUT    0         // float2[4096] = 8192 floats (.x=cos, .y=sin)
#define OFF_KRINV  8192      // 1024: 1/(1+|w_key|)
#define OFF_KB     9216      // 1024: b_key
#define OFF_QCOS   10240     // 16384
#define OFF_QSIN   26624     // 16384
#define OFF_ROWMAX 43008     // 256
#define OFF_ROWINV 43264     // 256
#define OFF_WSUM   43520     // 65536
#define OFF_SCORES 109056    // 1048576 (reused as partials by k_ctx/k_out)
// total = 1157632 floats = 4.42 MiB

__global__ __launch_bounds__(256) void k_init(const float* __restrict__ wk,
                                              const float* __restrict__ bk,
                                              float* __restrict__ ws) {
    int gid = blockIdx.x * 256 + threadIdx.x;
    float2* lut = (float2*)(ws + OFF_LUT);
    if (gid < LUTN) {
        float ang = (float)gid * ANGF;
        lut[gid] = make_float2(cosf(ang), sinf(ang));
    }
    if (gid < ND) {
        ws[OFF_KRINV + gid] = 1.0f / (1.0f + fabsf(wk[gid]));
        ws[OFF_KB + gid] = bk[gid];
    }
}

__global__ __launch_bounds__(256) void k_queries(const float* __restrict__ x,
                                                 const float* __restrict__ t,
                                                 const float* __restrict__ wq,
                                                 const float* __restrict__ bq,
                                                 float* __restrict__ ws) {
    int gid = blockIdx.x * 256 + threadIdx.x;   // NB*ND
    int b = gid >> 10, m = gid & 1023;
    const float2* lut = (const float2*)(ws + OFF_LUT);
    float theta = x[gid] / (1.0f + fabsf(wq[m])) + bq[m] + t[b] * PHIF;
    int idx = ((int)rintf(theta * KF)) & (LUTN - 1);
    float2 e = lut[idx];
    ws[OFF_QCOS + gid] = e.x;
    ws[OFF_QSIN + gid] = e.y;
}

__global__ __launch_bounds__(256) void k_scores(const float* __restrict__ cached,
                                                float* __restrict__ ws) {
    __shared__ float2 slut[LUTN];      // 32 KiB
    __shared__ float ssc[NH * TS];     // 4 KiB transpose buffer
    int tid = threadIdx.x;
    int bid = blockIdx.x;
    int b = bid / (NS / TS);
    int s0 = (bid % (NS / TS)) * TS;

    // stage LUT: 2048 float4 over 256 threads
    const float4* lutg4 = (const float4*)(ws + OFF_LUT);
    float4* slut4 = (float4*)slut;
    #pragma unroll
    for (int j = 0; j < 8; ++j)
        slut4[tid + j * 256] = lutg4[tid + j * 256];

    int m = tid * 4;
    float4 kr = *(const float4*)(ws + OFF_KRINV + m);
    float4 kb = *(const float4*)(ws + OFF_KB + m);
    float4 qc = *(const float4*)(ws + OFF_QCOS + b * ND + m);
    float4 qs = *(const float4*)(ws + OFF_QSIN + b * ND + m);
    __syncthreads();

    const float* base = cached + ((size_t)b * NS + s0) * ND + m;
    #pragma unroll 4
    for (int si = 0; si < TS; ++si) {
        float4 v = *(const float4*)(base + (size_t)si * ND);
        float p = 0.f;
        {
            float th = fmaf(v.x, kr.x, kb.x);
            int i0 = ((int)rintf(th * KF)) & (LUTN - 1);
            float2 e = slut[i0];
            p = fmaf(qc.x, e.x, p); p = fmaf(qs.x, e.y, p);
        }
        {
            float th = fmaf(v.y, kr.y, kb.y);
            int i0 = ((int)rintf(th * KF)) & (LUTN - 1);
            float2 e = slut[i0];
            p = fmaf(qc.y, e.x, p); p = fmaf(qs.y, e.y, p);
        }
        {
            float th = fmaf(v.z, kr.z, kb.z);
            int i0 = ((int)rintf(th * KF)) & (LUTN - 1);
            float2 e = slut[i0];
            p = fmaf(qc.z, e.x, p); p = fmaf(qs.z, e.y, p);
        }
        {
            float th = fmaf(v.w, kr.w, kb.w);
            int i0 = ((int)rintf(th * KF)) & (LUTN - 1);
            float2 e = slut[i0];
            p = fmaf(qc.w, e.x, p); p = fmaf(qs.w, e.y, p);
        }
        // reduce over the 16 lanes covering one head
        p += __shfl_xor(p, 1, 16);
        p += __shfl_xor(p, 2, 16);
        p += __shfl_xor(p, 4, 16);
        p += __shfl_xor(p, 8, 16);
        if ((tid & 15) == 0) ssc[(tid >> 4) * TS + si] = p * INV_SCALE;
    }
    __syncthreads();
    // coalesced scores write: [b][h][s0..s0+63], 1024 floats
    float* srow = ws + OFF_SCORES + (size_t)b * NH * NS;
    int h = tid >> 4;
    int si = (tid & 15) * 4;
    float4 st = *(const float4*)(ssc + tid * 4);
    *(float4*)(srow + (size_t)h * NS + s0 + si) = st;
}

__global__ __launch_bounds__(256) void k_rowstats(float* __restrict__ ws) {
    int row = blockIdx.x;   // NB*NH
    int tid = threadIdx.x;
    const float4* sr = (const float4*)(ws + OFF_SCORES + (size_t)row * NS);
    float4 r[4];
    float mx = -1e30f;
    #pragma unroll
    for (int j = 0; j < 4; ++j) {
        r[j] = sr[tid + j * 256];
        mx = fmaxf(mx, fmaxf(fmaxf(r[j].x, r[j].y), fmaxf(r[j].z, r[j].w)));
    }
    #pragma unroll
    for (int off = 32; off > 0; off >>= 1) mx = fmaxf(mx, __shfl_xor(mx, off));
    __shared__ float redm[4];
    __shared__ float reds[4];
    int wv = tid >> 6, ln = tid & 63;
    if (ln == 0) redm[wv] = mx;
    __syncthreads();
    mx = fmaxf(fmaxf(redm[0], redm[1]), fmaxf(redm[2], redm[3]));
    float sum = 0.f;
    #pragma unroll
    for (int j = 0; j < 4; ++j) {
        sum += expf(r[j].x - mx);
        sum += expf(r[j].y - mx);
        sum += expf(r[j].z - mx);
        sum += expf(r[j].w - mx);
    }
    #pragma unroll
    for (int off = 32; off > 0; off >>= 1) sum += __shfl_xor(sum, off);
    if (ln == 0) reds[wv] = sum;
    __syncthreads();
    if (tid == 0) {
        float s = ((reds[0] + reds[1]) + (reds[2] + reds[3]));
        ws[OFF_ROWMAX + row] = mx;
        ws[OFF_ROWINV + row] = 1.0f / s;
    }
}

__global__ __launch_bounds__(256) void k_wsum(float* __restrict__ ws) {
    int gid = blockIdx.x * 256 + threadIdx.x;  // NB*NS
    int b = gid >> 12;
    int s = gid & 4095;
    float acc = 0.f;
    #pragma unroll
    for (int h = 0; h < NH; ++h) {
        int row = b * NH + h;
        acc += expf(ws[OFF_SCORES + (size_t)row * NS + s] - ws[OFF_ROWMAX + row])
               * ws[OFF_ROWINV + row];
    }
    ws[OFF_WSUM + gid] = acc;
}

__global__ __launch_bounds__(256) void k_ctx(const float* __restrict__ cached,
                                             float* __restrict__ ws) {
    int bid = blockIdx.x;             // NB*NCHUNK
    int b = bid / NCHUNK, c = bid % NCHUNK;
    int s0 = c * (NS / NCHUNK);
    int tid = threadIdx.x;
    const float* base = cached + ((size_t)b * NS + s0) * ND + tid * 4;
    const float* wp = ws + OFF_WSUM + b * NS + s0;
    float4 acc = {0.f, 0.f, 0.f, 0.f};
    #pragma unroll 4
    for (int si = 0; si < NS / NCHUNK; ++si) {
        float w = wp[si];
        float4 v = *(const float4*)(base + (size_t)si * ND);
        acc.x = fmaf(w, v.x, acc.x);
        acc.y = fmaf(w, v.y, acc.y);
        acc.z = fmaf(w, v.z, acc.z);
        acc.w = fmaf(w, v.w, acc.w);
    }
    // partials reuse the scores region (scores are dead after k_wsum)
    *(float4*)(ws + OFF_SCORES + ((size_t)c * NB + b) * ND + tid * 4) = acc;
}

__global__ __launch_bounds__(256) void k_out(const float* __restrict__ t,
                                             const float* __restrict__ wo,
                                             const float* __restrict__ bo,
                                             const float* __restrict__ osc,
                                             const float* __restrict__ ws,
                                             float* __restrict__ out) {
    int gid = blockIdx.x * 256 + threadIdx.x;  // NB*ND
    int b = gid >> 10, m = gid & 1023;
    float acc = 0.f;
    const float* part = ws + OFF_SCORES;
    #pragma unroll 8
    for (int c = 0; c < NCHUNK; ++c)
        acc += part[((size_t)c * NB + b) * ND + m];
    float theta = acc / (1.0f + fabsf(wo[m])) + bo[m] + t[b] * PHIF;
    int idx = ((int)rintf(theta * KF)) & (LUTN - 1);
    const float2* lut = (const float2*)(ws + OFF_LUT);
    float2 e = lut[idx];
    out[gid] = osc[m] * (e.x + e.y);
}

extern "C" void kernel_launch(void* const* d_in, const int* in_sizes, int n_in,
                              void* d_out, int out_size, void* d_ws, size_t ws_size,
                              hipStream_t stream) {
    const float* x      = (const float*)d_in[0];
    const float* cached = (const float*)d_in[1];
    const float* t      = (const float*)d_in[2];
    const float* wq     = (const float*)d_in[3];
    const float* bq     = (const float*)d_in[4];
    const float* wk     = (const float*)d_in[5];
    const float* bk     = (const float*)d_in[6];
    const float* wo     = (const float*)d_in[7];
    const float* bo     = (const float*)d_in[8];
    const float* osc    = (const float*)d_in[9];
    float* ws  = (float*)d_ws;
    float* out = (float*)d_out;

    k_init<<<LUTN / 256, 256, 0, stream>>>(wk, bk, ws);
    k_queries<<<NB * ND / 256, 256, 0, stream>>>(x, t, wq, bq, ws);
    k_scores<<<NB * (NS / TS), 256, 0, stream>>>(cached, ws);
    k_rowstats<<<NB * NH, 256, 0, stream>>>(ws);
    k_wsum<<<NB * NS / 256, 256, 0, stream>>>(ws);
    k_ctx<<<NB * NCHUNK, 256, 0, stream>>>(cached, ws);
    k_out<<<NB * ND / 256, 256, 0, stream>>>(t, wo, bo, osc, ws, out);
}

// Round 2
// 103.229 us; speedup vs baseline: 1.1949x; 1.1949x over previous
//
#include <hip/hip_runtime.h>
#include <math.h>

#define NB 16
#define NS 4096
#define ND 1024
#define NH 16
#define LUTN 4096
#define TS 32        // s-rows per block in k_scores
#define NCHUNK 64    // s-chunks in k_ctx

#define KF   651.8986469044033f      // LUT_SIZE / (2*pi)
#define PHIF 1.6180339887498949f
#define ANGF 0.0015339807878856412f  // 2*pi / LUT_SIZE
#define INV_SCALE (1.0f / 11.313708498984761f)  // 1/sqrt(2*dh)

// workspace layout, in floats
#define OFF_E     0          // exp(scores) [NB][NH][NS] = 1048576 floats
#define OFF_INVZ  1048576    // 256: 1/sum per (b,h)
#define OFF_WSUM  1048832    // 65536: per-(b,s) collapsed weight
#define OFF_PART  1114368    // [NCHUNK][NB][ND] = 1048576 context partials

// quantized-angle fast sincos: matches LUT semantics, hw trans pipe.
__device__ __forceinline__ float2 qsincos_fast(float theta) {
    float idxf = rintf(theta * KF);
    float ang = idxf * ANGF;           // radians; __sinf/__cosf use v_sin/v_cos
    return make_float2(__cosf(ang), __sinf(ang));
}

__global__ __launch_bounds__(256) void k_scores(const float* __restrict__ cached,
                                                const float* __restrict__ x,
                                                const float* __restrict__ t,
                                                const float* __restrict__ wq,
                                                const float* __restrict__ bq,
                                                const float* __restrict__ wk,
                                                const float* __restrict__ bk,
                                                float* __restrict__ ws) {
    __shared__ float ssc[NH * TS];     // 2 KiB transpose buffer
    int tid = threadIdx.x;
    int bid = blockIdx.x;
    int b = bid / (NS / TS);
    int s0 = (bid % (NS / TS)) * TS;
    int m = tid * 4;

    // per-thread key params
    float4 wkv = *(const float4*)(wk + m);
    float4 kbv = *(const float4*)(bk + m);
    float4 kr;
    kr.x = 1.0f / (1.0f + fabsf(wkv.x));
    kr.y = 1.0f / (1.0f + fabsf(wkv.y));
    kr.z = 1.0f / (1.0f + fabsf(wkv.z));
    kr.w = 1.0f / (1.0f + fabsf(wkv.w));

    // per-thread query fragment (recomputed per block; x/wq/bq are L2-hot)
    float tphi = t[b] * PHIF;
    float4 xv = *(const float4*)(x + b * ND + m);
    float4 wqv = *(const float4*)(wq + m);
    float4 bqv = *(const float4*)(bq + m);
    float2 q0 = qsincos_fast(xv.x / (1.0f + fabsf(wqv.x)) + bqv.x + tphi);
    float2 q1 = qsincos_fast(xv.y / (1.0f + fabsf(wqv.y)) + bqv.y + tphi);
    float2 q2 = qsincos_fast(xv.z / (1.0f + fabsf(wqv.z)) + bqv.z + tphi);
    float2 q3 = qsincos_fast(xv.w / (1.0f + fabsf(wqv.w)) + bqv.w + tphi);

    const float* base = cached + ((size_t)b * NS + s0) * ND + m;
    #pragma unroll 4
    for (int si = 0; si < TS; ++si) {
        float4 v = *(const float4*)(base + (size_t)si * ND);
        float2 e0 = qsincos_fast(fmaf(v.x, kr.x, kbv.x));
        float2 e1 = qsincos_fast(fmaf(v.y, kr.y, kbv.y));
        float2 e2 = qsincos_fast(fmaf(v.z, kr.z, kbv.z));
        float2 e3 = qsincos_fast(fmaf(v.w, kr.w, kbv.w));
        float p;
        p = q0.x * e0.x;
        p = fmaf(q0.y, e0.y, p);
        p = fmaf(q1.x, e1.x, p);
        p = fmaf(q1.y, e1.y, p);
        p = fmaf(q2.x, e2.x, p);
        p = fmaf(q2.y, e2.y, p);
        p = fmaf(q3.x, e3.x, p);
        p = fmaf(q3.y, e3.y, p);
        // reduce over the 16 lanes covering one head
        p += __shfl_xor(p, 1, 16);
        p += __shfl_xor(p, 2, 16);
        p += __shfl_xor(p, 4, 16);
        p += __shfl_xor(p, 8, 16);
        if ((tid & 15) == 0) ssc[(tid >> 4) * TS + si] = p * INV_SCALE;
    }
    __syncthreads();
    // coalesced exp(score) write: 512 values, 2 per thread
    int i0 = tid * 2;
    int h = i0 >> 5;          // /TS
    int sl = i0 & 31;
    float2 ev;
    ev.x = __expf(ssc[i0]);
    ev.y = __expf(ssc[i0 + 1]);
    *(float2*)(ws + OFF_E + ((size_t)(b * NH + h)) * NS + s0 + sl) = ev;
}

__global__ __launch_bounds__(256) void k_zsum(float* __restrict__ ws) {
    int row = blockIdx.x;   // NB*NH
    int tid = threadIdx.x;
    const float4* sr = (const float4*)(ws + OFF_E + (size_t)row * NS);
    float sum = 0.f;
    #pragma unroll
    for (int j = 0; j < 4; ++j) {
        float4 r = sr[tid + j * 256];
        sum += (r.x + r.y) + (r.z + r.w);
    }
    #pragma unroll
    for (int off = 32; off > 0; off >>= 1) sum += __shfl_xor(sum, off);
    __shared__ float reds[4];
    int wv = tid >> 6, ln = tid & 63;
    if (ln == 0) reds[wv] = sum;
    __syncthreads();
    if (tid == 0)
        ws[OFF_INVZ + row] = 1.0f / ((reds[0] + reds[1]) + (reds[2] + reds[3]));
}

__global__ __launch_bounds__(256) void k_wsum(float* __restrict__ ws) {
    int gid = blockIdx.x * 256 + threadIdx.x;  // NB*NS
    int b = gid >> 12;
    int s = gid & 4095;
    float acc = 0.f;
    #pragma unroll
    for (int h = 0; h < NH; ++h) {
        int row = b * NH + h;
        acc = fmaf(ws[OFF_E + (size_t)row * NS + s], ws[OFF_INVZ + row], acc);
    }
    ws[OFF_WSUM + gid] = acc;
}

__global__ __launch_bounds__(256) void k_ctx(const float* __restrict__ cached,
                                             float* __restrict__ ws) {
    int bid = blockIdx.x;             // NB*NCHUNK
    int b = bid / NCHUNK, c = bid % NCHUNK;
    int s0 = c * (NS / NCHUNK);
    int tid = threadIdx.x;
    const float* base = cached + ((size_t)b * NS + s0) * ND + tid * 4;
    const float* wp = ws + OFF_WSUM + b * NS + s0;
    float4 acc = {0.f, 0.f, 0.f, 0.f};
    #pragma unroll 4
    for (int si = 0; si < NS / NCHUNK; ++si) {
        float w = wp[si];
        float4 v = *(const float4*)(base + (size_t)si * ND);
        acc.x = fmaf(w, v.x, acc.x);
        acc.y = fmaf(w, v.y, acc.y);
        acc.z = fmaf(w, v.z, acc.z);
        acc.w = fmaf(w, v.w, acc.w);
    }
    *(float4*)(ws + OFF_PART + ((size_t)c * NB + b) * ND + tid * 4) = acc;
}

__global__ __launch_bounds__(256) void k_out(const float* __restrict__ t,
                                             const float* __restrict__ wo,
                                             const float* __restrict__ bo,
                                             const float* __restrict__ osc,
                                             const float* __restrict__ ws,
                                             float* __restrict__ out) {
    int gid = blockIdx.x * 256 + threadIdx.x;  // NB*ND
    int b = gid >> 10, m = gid & 1023;
    float acc = 0.f;
    const float* part = ws + OFF_PART;
    #pragma unroll 8
    for (int c = 0; c < NCHUNK; ++c)
        acc += part[((size_t)c * NB + b) * ND + m];
    float theta = acc / (1.0f + fabsf(wo[m])) + bo[m] + t[b] * PHIF;
    int idx = ((int)rintf(theta * KF)) & (LUTN - 1);
    float ang = (float)idx * ANGF;
    // precise libm trig: bit-matches the np table entries
    out[gid] = osc[m] * (cosf(ang) + sinf(ang));
}

extern "C" void kernel_launch(void* const* d_in, const int* in_sizes, int n_in,
                              void* d_out, int out_size, void* d_ws, size_t ws_size,
                              hipStream_t stream) {
    const float* x      = (const float*)d_in[0];
    const float* cached = (const float*)d_in[1];
    const float* t      = (const float*)d_in[2];
    const float* wq     = (const float*)d_in[3];
    const float* bq     = (const float*)d_in[4];
    const float* wk     = (const float*)d_in[5];
    const float* bk     = (const float*)d_in[6];
    const float* wo     = (const float*)d_in[7];
    const float* bo     = (const float*)d_in[8];
    const float* osc    = (const float*)d_in[9];
    float* ws  = (float*)d_ws;
    float* out = (float*)d_out;

    k_scores<<<NB * (NS / TS), 256, 0, stream>>>(cached, x, t, wq, bq, wk, bk, ws);
    k_zsum<<<NB * NH, 256, 0, stream>>>(ws);
    k_wsum<<<NB * NS / 256, 256, 0, stream>>>(ws);
    k_ctx<<<NB * NCHUNK, 256, 0, stream>>>(cached, ws);
    k_out<<<NB * ND / 256, 256, 0, stream>>>(t, wo, bo, osc, ws, out);
}